// Round 2
// baseline (108.531 us; speedup 1.0000x reference)
//
#include <hip/hip_runtime.h>
#include <math.h>

#define NH 192
#define NW 192
#define Wt 193
#define TG 24              // tiles per dim (192/8)
#define NTILE (TG*TG)      // 576
#define TILE_SZ 4096       // 64 j * 64 p
#define TBLK 3072          // table-builder blocks in fused prep kernel

// cos(2*pi*num/den) via HW cos (input in revolutions)
__device__ __forceinline__ float cos_rev(float num, float den) {
    float rev = num * __builtin_amdgcn_rcpf(den);
    rev = __builtin_amdgcn_fractf(rev);
    return __builtin_amdgcn_cosf(rev);
}

// ---------------- fused prep: tables + x ----------------
// blocks [0,TBLK): build both cos tables, SAME layout (one cos, two writes):
//   Cz [j][kg][i][r] = cos(2*pi*(kg*4+r)/(i*64+j+2))            (k2 side)
//   CP1[j][kg][i][r] = cos(2*pi*(kg*4+r)/(i*64+j+2)) * P[i][j]  (k1 side)
// blocks [TBLK, TBLK+576): xt[tile][j][p] = (win_avg @ M^T), p = l1*8+l2 local
__global__ __launch_bounds__(256) void k_prep(const float* __restrict__ grid,
                                              const float* __restrict__ Mw,
                                              const float* __restrict__ P,
                                              float* __restrict__ Cz,
                                              float* __restrict__ CP1,
                                              float* __restrict__ xt) {
    __shared__ float Ms[64 * 64];    // M[j][c]
    __shared__ float win[64 * 68];   // win[p][c], stride 68
    int bx = blockIdx.x;
    int t = threadIdx.x;

    if (bx < TBLK) {
        int idx = bx * 256 + t;                 // 0..786431
        int r  = idx & 3;
        int i  = (idx >> 2) & 63;
        int kg = (idx >> 8) % 48;
        int j  = idx / 12288;
        int k  = kg * 4 + r;
        int t2 = i * 64 + j;
        float c = cos_rev((float)k, (float)(t2 + 2));
        Cz[idx]  = c;                // coalesced
        CP1[idx] = c * P[t2];        // coalesced store, P gather L1-resident
        return;
    }

    int bb = bx - TBLK;                         // 0..575
    int k1g = bb % TG, k2g = bb / TG;

    // stage M (coalesced)
    #pragma unroll
    for (int r = 0; r < 4; ++r) {
        int e = r * 256 + t;
        ((float4*)Ms)[e] = ((const float4*)Mw)[e];
    }

    // window averages: lane = channel c
    {
        int c = t & 63, pq = t >> 6;
        const float* gb = grid + ((size_t)(k1g * 8) * Wt + k2g * 8) * 64;
        #pragma unroll
        for (int r = 0; r < 16; ++r) {
            int p = pq * 16 + r;
            int l1 = p >> 3, l2 = p & 7;
            const float* g0 = gb + ((size_t)l1 * Wt + l2) * 64;
            float s = g0[c] + g0[64 + c] + g0[Wt * 64 + c] + g0[Wt * 64 + 64 + c];
            win[p * 68 + c] = 0.25f * s;
        }
    }
    __syncthreads();

    // x[p][j] = sum_c win[p][c] * M[j][c]; lane = p -> coalesced stores
    int p = t & 63, jq = t >> 6;
    float4 wv[16];
    #pragma unroll
    for (int q = 0; q < 16; ++q) wv[q] = *(const float4*)&win[p * 68 + 4 * q];

    float* xb = xt + (size_t)(k1g * TG + k2g) * TILE_SZ;
    #pragma unroll
    for (int r = 0; r < 16; ++r) {
        int j = jq * 16 + r;
        float acc = 0.f;
        #pragma unroll
        for (int q = 0; q < 16; ++q) {
            float4 mv = *(const float4*)&Ms[j * 64 + 4 * q];   // uniform broadcast
            acc += wv[q].x * mv.x + wv[q].y * mv.y + wv[q].z * mv.z + wv[q].w * mv.w;
        }
        xb[(size_t)j * 64 + p] = acc;    // coalesced
    }
}

// ---------------- k_main v3: Nk[b,i] ----------------
// 256 thr = 4 waves; tile = 8x8 pairs; wave w -> (h1,h2) = (w&1, w>>1);
// each thread owns a 4x4 (k1,k2) sub-tile for lane = i.
// Rationale (LDS/VALU balance): per jj a thread reads 4B*(4+4)=32B LDS for
// 16 pairs (1.0 cy/pair) vs v1's 36B for 8 pairs (2.25 cy/pair). LDS read
// traffic per output drops 2.25x -> LDS and VALU pipes balanced at ~144cy/jj/CU.
// Staging: global_load_lds width=16 (wave-uniform base + lane*16), 32KB/chunk
// of 8 jj (c1 16KB + c2 16KB) -> same LDS capacity as best-measured v1.
__global__ __launch_bounds__(256) void k_main(const float* __restrict__ xt,
                                              const float* __restrict__ Cz,
                                              const float* __restrict__ CP1,
                                              float* __restrict__ out) {
    __shared__ float4 ls[2048];      // 32 KB: c1 [0,1024): [jj(8)][g(2)][i(64)]
                                     //        c2 [1024,2048): same shape
    int bx = blockIdx.x;
    // bijective 2D XCD swizzle: residue class (bx&7) -> 12x6 tile rectangle
    // per-XCD tables: 12*128KB (c1) + 6*128KB (c2) = 2.25MB < 4MiB L2
    int xcd = bx & 7, q = bx >> 3;               // 576 = 8 * 72
    int k1g = (xcd & 1) * 12 + (q % 12);         // 2 x 12 = 24
    int k2g = (xcd >> 1) * 6 + (q / 12);         // 4 x 6  = 24
    int t = threadIdx.x;
    int lane = t & 63;               // i
    int w  = __builtin_amdgcn_readfirstlane(t >> 6);  // 0..3
    int h1 = w & 1, h2 = w >> 1;

    const float4* Cz4 = (const float4*)Cz;
    const float4* CP4 = (const float4*)CP1;
    // x: wave-uniform pointer -> s_load; p = l1*8+l2 = (h1*4+a)*8 + h2*4+b
    const float*  xb  = xt + (size_t)(k1g * TG + k2g) * TILE_SZ + h1 * 32 + h2 * 4;
    int c1base = k1g * 2;            // kg base on c1 side
    int c2base = k2g * 2;            // kg base on c2 side

    float4 acc[4];
    #pragma unroll
    for (int a = 0; a < 4; ++a) acc[a] = (float4){0.f, 0.f, 0.f, 0.f};

    for (int jc = 0; jc < 8; ++jc) {
        __syncthreads();             // previous chunk fully consumed
        #pragma unroll
        for (int r = 0; r < 8; ++r) {
            int e = r * 256 + t;     // [0,2048); lane-stride 16B in LDS
            const float4* src;
            if (r < 4) {             // c1 slice: [jj][g][i]
                int jj = e >> 7, g = (e >> 6) & 1, i = e & 63;
                src = CP4 + ((size_t)((jc * 8 + jj) * 48 + c1base + g) * 64 + i);
            } else {                 // c2 slice
                int e2 = e - 1024;
                int jj = e2 >> 7, g = (e2 >> 6) & 1, i = e2 & 63;
                src = Cz4 + ((size_t)((jc * 8 + jj) * 48 + c2base + g) * 64 + i);
            }
            __builtin_amdgcn_global_load_lds(
                (const __attribute__((address_space(1))) unsigned int*)src,
                (__attribute__((address_space(3))) unsigned int*)&ls[e], 16, 0, 0);
        }
        __syncthreads();             // compiler drains vmcnt before barrier

        #pragma unroll
        for (int jj = 0; jj < 8; ++jj) {
            int j = jc * 8 + jj;
            float4 A = ls[(jj * 2 + h1) * 64 + lane];          // 4 k1 vals, b128 cf
            float4 B = ls[1024 + (jj * 2 + h2) * 64 + lane];   // 4 k2 vals, b128 cf
            const float4* xj = (const float4*)(xb + (size_t)j * 64);  // uniform
            float4 x0 = xj[0];       // a=0: p offsets +0..3
            float4 x1 = xj[2];       // a=1: +8
            float4 x2 = xj[4];       // a=2: +16
            float4 x3 = xj[6];       // a=3: +24
            float Af[4] = {A.x, A.y, A.z, A.w};
            float4 xs[4] = {x0, x1, x2, x3};
            #pragma unroll
            for (int a = 0; a < 4; ++a) {
                acc[a].x += xs[a].x * (Af[a] * B.x);
                acc[a].y += xs[a].y * (Af[a] * B.y);
                acc[a].z += xs[a].z * (Af[a] * B.z);
                acc[a].w += xs[a].w * (Af[a] * B.w);
            }
        }
    }

    // out[(k1*192 + k2)*64 + i], k1 = k1g*8+h1*4+a, k2 = k2g*8+h2*4+b
    int k1b = k1g * 8 + h1 * 4;
    int k2b = k2g * 8 + h2 * 4;
    #pragma unroll
    for (int a = 0; a < 4; ++a) {
        size_t ob = ((size_t)(k1b + a) * NW + k2b) * 64 + lane;
        out[ob]           = acc[a].x;   // coalesced dword stores
        out[ob + 64]      = acc[a].y;
        out[ob + 128]     = acc[a].z;
        out[ob + 192]     = acc[a].w;
    }
}

extern "C" void kernel_launch(void* const* d_in, const int* in_sizes, int n_in,
                              void* d_out, int out_size, void* d_ws, size_t ws_size,
                              hipStream_t stream) {
    const float* grid = (const float*)d_in[0];   // [193,193,64]
    const float* Mw   = (const float*)d_in[1];   // [64,64]
    const float* P    = (const float*)d_in[2];   // [64,64]
    float* out = (float*)d_out;                  // [36864,64]

    // ws layout (floats): Cz [786432] | CP1 [786432] | xt [576*4096]
    float* Cz  = (float*)d_ws;
    float* CP1 = Cz + 786432;
    float* xt  = CP1 + 786432;

    k_prep<<<TBLK + NTILE, 256, 0, stream>>>(grid, Mw, P, Cz, CP1, xt);
    k_main<<<NTILE, 256, 0, stream>>>(xt, Cz, CP1, out);
}

// Round 4
// 96.370 us; speedup vs baseline: 1.1262x; 1.1262x over previous
//
#include <hip/hip_runtime.h>
#include <math.h>

#define NH 192
#define NW 192
#define Wt 193
#define TG 24              // tiles per dim (192/8)
#define NTILE (TG*TG)      // 576
#define TILE_SZ 4096       // 64 j * 64 p
#define TBLK 3072          // table-builder blocks in fused prep kernel

// cos(2*pi*num/den) via HW cos (input in revolutions)
__device__ __forceinline__ float cos_rev(float num, float den) {
    float rev = num * __builtin_amdgcn_rcpf(den);
    rev = __builtin_amdgcn_fractf(rev);
    return __builtin_amdgcn_cosf(rev);
}

// ---------------- fused prep: tables + x ----------------
// EXACT round-0 version (passed twice). blocks [0,TBLK): build both tables:
//   Cz [j][kg][i][r] = cos(2*pi*(kg*4+r)/(i*64+j+2))          (k2 side, float4-packed)
//   CP1[j][k][i]     = cos(2*pi*k/(i*64+j+2)) * P[i][j]       (k1 side, row-packed)
// blocks [TBLK, TBLK+576): xt[tile][j][p] = (win_avg @ M^T), p = l1*8+l2 local
__global__ __launch_bounds__(256) void k_prep(const float* __restrict__ grid,
                                              const float* __restrict__ Mw,
                                              const float* __restrict__ P,
                                              float* __restrict__ Cz,
                                              float* __restrict__ CP1,
                                              float* __restrict__ xt) {
    __shared__ float Ms[64 * 64];    // M[j][c]
    __shared__ float win[64 * 68];   // win[p][c], stride 68
    int bx = blockIdx.x;
    int t = threadIdx.x;

    if (bx < TBLK) {
        int idx = bx * 256 + t;                 // 0..786431
        // Cz entry
        int r  = idx & 3;
        int i  = (idx >> 2) & 63;
        int kg = (idx >> 8) % 48;
        int j  = idx / 12288;
        int k  = kg * 4 + r;
        Cz[idx] = cos_rev((float)k, (float)(i * 64 + j + 2));
        // CP1 entry (different mapping, same flat size): [j][k][i] layout
        int i2 = idx & 63;
        int k2 = (idx >> 6) % 192;
        int j2 = idx / 12288;
        int t2 = i2 * 64 + j2;
        CP1[idx] = cos_rev((float)k2, (float)(t2 + 2)) * P[t2];
        return;
    }

    int bb = bx - TBLK;                         // 0..575
    int k1g = bb % TG, k2g = bb / TG;

    // stage M (coalesced)
    #pragma unroll
    for (int r = 0; r < 4; ++r) {
        int e = r * 256 + t;
        ((float4*)Ms)[e] = ((const float4*)Mw)[e];
    }

    // window averages: lane = channel c
    {
        int c = t & 63, pq = t >> 6;
        const float* gb = grid + ((size_t)(k1g * 8) * Wt + k2g * 8) * 64;
        #pragma unroll
        for (int r = 0; r < 16; ++r) {
            int p = pq * 16 + r;
            int l1 = p >> 3, l2 = p & 7;
            const float* g0 = gb + ((size_t)l1 * Wt + l2) * 64;
            float s = g0[c] + g0[64 + c] + g0[Wt * 64 + c] + g0[Wt * 64 + 64 + c];
            win[p * 68 + c] = 0.25f * s;
        }
    }
    __syncthreads();

    // x[p][j] = sum_c win[p][c] * M[j][c]; lane = p -> coalesced stores
    int p = t & 63, jq = t >> 6;
    float4 wv[16];
    #pragma unroll
    for (int q = 0; q < 16; ++q) wv[q] = *(const float4*)&win[p * 68 + 4 * q];

    float* xb = xt + (size_t)(k1g * TG + k2g) * TILE_SZ;
    #pragma unroll
    for (int r = 0; r < 16; ++r) {
        int j = jq * 16 + r;
        float acc = 0.f;
        #pragma unroll
        for (int q = 0; q < 16; ++q) {
            float4 mv = *(const float4*)&Ms[j * 64 + 4 * q];   // uniform broadcast
            acc += wv[q].x * mv.x + wv[q].y * mv.y + wv[q].z * mv.z + wv[q].w * mv.w;
        }
        xb[(size_t)j * 64 + p] = acc;    // coalesced
    }
}

// ---------------- k_main v4b: Nk[b,i] ----------------
// v1 schedule (512 thr = 8 waves, 576 blocks, 32KB c2-only LDS, 4 chunks,
// unroll 4, identical staging loop), per-thread tile reshaped 1x8 -> 2x4:
//   wave w: h1 = w&3 -> k1 = k1g*8 + 2h1 + a (a=0,1)
//           h2 = w>>2 -> k2 = k2g*8 + 4h2 + b (b=0..3).  lane = i.
// Per jj: 1x ds_read_b128 (c2 quad, 16B) + 2 coalesced global dwords (c1
// pair, L2-hot, each shared by 2 waves) + 2 s_load_dwordx4 (x, uniform)
// + 16 VALU. LDS demand 2.0 -> 1.0 B/VALU-op; block LDS read 1MB -> 512KB.
__global__ __launch_bounds__(512) void k_main(const float* __restrict__ xt,
                                              const float* __restrict__ Cz,
                                              const float* __restrict__ CP1,
                                              float* __restrict__ out) {
    __shared__ float4 cs[2048];      // 32 KB: [jj(16)][g(2)][i(64)]
    int bx = blockIdx.x;             // consecutive blocks share k2g (c2 slice hot)
    int k1g = bx % TG, k2g = bx / TG;
    int t = threadIdx.x;
    int lane = t & 63;               // i
    int w = __builtin_amdgcn_readfirstlane(t >> 6);   // 0..7
    int h1 = w & 3;                  // k1 pair select (0..3)
    int h2 = w >> 2;                 // k2 quad select (0..1)

    // c1 base: k1 = k1g*8 + 2*h1; reads at +j*12288 and +j*12288+64
    const float*  c1p = CP1 + (size_t)(k1g * 8 + 2 * h1) * 64 + lane;
    const float*  xb  = xt + (size_t)(k1g * TG + k2g) * TILE_SZ;       // uniform
    const float4* Cz4 = (const float4*)Cz;
    int kgb = k2g * 2;

    float4 acc0 = (float4){0.f, 0.f, 0.f, 0.f};   // a=0, b=0..3
    float4 acc1 = (float4){0.f, 0.f, 0.f, 0.f};   // a=1, b=0..3

    for (int jc = 0; jc < 4; ++jc) {
        __syncthreads();             // previous chunk fully consumed
        #pragma unroll
        for (int r = 0; r < 4; ++r) {
            int e = r * 512 + t;     // [0,2048): jj = e>>7, g = (e>>6)&1, i = e&63
            int jj = e >> 7;
            int g  = (e >> 6) & 1;
            int i  = e & 63;
            cs[e] = Cz4[(size_t)((jc * 16 + jj) * 48 + kgb + g) * 64 + i];  // coalesced
        }
        __syncthreads();

        #pragma unroll 4
        for (int jj = 0; jj < 16; ++jj) {
            int j = jc * 16 + jj;
            float ca = c1p[(size_t)j * 12288];           // c1, k1 = ..+2h1   (coalesced)
            float cb = c1p[(size_t)j * 12288 + 64];      // c1, k1 = ..+2h1+1 (coalesced)
            float4 B = cs[jj * 128 + h2 * 64 + lane];    // c2 quad, b128 conflict-free
            const float4* xj = (const float4*)(xb + (size_t)j * 64);  // uniform
            // p = (2h1+a)*8 + 4h2 + b  ->  float4 index = 4h1 + 2a + h2
            float4 x0 = xj[4 * h1 + h2];                 // a=0 (s_load_dwordx4)
            float4 x1 = xj[4 * h1 + h2 + 2];             // a=1
            acc0.x += x0.x * (ca * B.x); acc0.y += x0.y * (ca * B.y);
            acc0.z += x0.z * (ca * B.z); acc0.w += x0.w * (ca * B.w);
            acc1.x += x1.x * (cb * B.x); acc1.y += x1.y * (cb * B.y);
            acc1.z += x1.z * (cb * B.z); acc1.w += x1.w * (cb * B.w);
        }
    }

    // out[(k1*192 + k2)*64 + i]; k1 = k1g*8 + 2h1 + a, k2 = k2g*8 + 4h2 + b
    int k1b = k1g * 8 + 2 * h1;
    int k2b = k2g * 8 + 4 * h2;
    size_t ob0 = ((size_t)k1b * NW + k2b) * 64 + lane;
    out[ob0]       = acc0.x;         // coalesced dword stores
    out[ob0 + 64]  = acc0.y;
    out[ob0 + 128] = acc0.z;
    out[ob0 + 192] = acc0.w;
    size_t ob1 = ob0 + (size_t)NW * 64;   // k1b+1
    out[ob1]       = acc1.x;
    out[ob1 + 64]  = acc1.y;
    out[ob1 + 128] = acc1.z;
    out[ob1 + 192] = acc1.w;
}

extern "C" void kernel_launch(void* const* d_in, const int* in_sizes, int n_in,
                              void* d_out, int out_size, void* d_ws, size_t ws_size,
                              hipStream_t stream) {
    const float* grid = (const float*)d_in[0];   // [193,193,64]
    const float* Mw   = (const float*)d_in[1];   // [64,64]
    const float* P    = (const float*)d_in[2];   // [64,64]
    float* out = (float*)d_out;                  // [36864,64]

    // ws layout (floats): Cz [786432] | CP1 [786432] | xt [576*4096]
    float* Cz  = (float*)d_ws;
    float* CP1 = Cz + 786432;
    float* xt  = CP1 + 786432;

    k_prep<<<TBLK + NTILE, 256, 0, stream>>>(grid, Mw, P, Cz, CP1, xt);
    k_main<<<NTILE, 512, 0, stream>>>(xt, Cz, CP1, out);
}